// Round 10
// baseline (330.853 us; speedup 1.0000x reference)
//
#include <hip/hip_runtime.h>
#include <math.h>

#define NTOK 32768
#define DIM  1024
#define NE   7
#define TROW 448   // T_all row width (DP-prefix padded), bf16

// ws layout (4-byte units up to B16; AIMG/TALL byte offsets). ws ~512 MB.
#define PN_OFF   0        // 7*1024 normalized prototypes (f32)
#define R1_OFF   7168
#define R2_OFF   7176
#define R3_OFF   7184
#define CNT_OFF  7192     // 8 ints
#define PR1_OFF  7200     // 2048*8
#define PR2_OFF  23584    // 128*8
#define PR3_OFF  24608    // 128*8
#define E0_OFF   25632    // NTOK*8 exp(sim/kappa)
#define LG_OFF   287776   // NTOK: log(top-1 gate)
#define LIST_OFF 320544   // NE*NTOK ints
#define B16_OFF  754720   // bf16 B weights (padded cols)
#define AIMG_OFF_BYTES 3936384   // packed A image: 32 chunks * 12800 shorts = 800 KB
#define TALL_OFF_BYTES 4984960   // bf16 T_all [NTOK][448] = 29.4 MB
#define NBLK 2055

#define SEPS 1e-6f

typedef __attribute__((ext_vector_type(8))) short short8v;
typedef __attribute__((ext_vector_type(4))) float f32x4;

// per-expert geometry
constexpr int DV[7]   = {8, 16, 32, 48, 64, 96, 128};
constexpr int DPV[7]  = {32, 32, 32, 64, 64, 96, 128};   // K-padded
constexpr int DAPV[7] = {16, 16, 32, 48, 64, 96, 128};   // N-padded
constexpr int BOV[7]  = {0, 32768, 65536, 98304, 163840, 229376, 327680};
constexpr int APRE[7] = {0, 32, 64, 96, 160, 224, 320};  // DP-prefix col in T_all
constexpr int RSV[7]  = {0, 16, 32, 64, 112, 176, 272};  // DAP-prefix row in A-image
// T_all column base of global A-tile t (A rows 16t..16t+15), t = 0..24
constexpr int TCOL[25] = {0, 32, 64, 80, 96, 112, 128, 160, 176, 192, 208,
                          224, 240, 256, 272, 288, 304,
                          320, 336, 352, 368, 384, 400, 416, 432};
// per-wave tile quarters and sim-expert split
constexpr int TQ0[4] = {0, 7, 13, 19};
constexpr int TQN[4] = {7, 6, 6, 6};
constexpr int SE0[4] = {0, 2, 4, 6};
constexpr int SEN[4] = {2, 2, 2, 1};

struct ExpPtrs { const float* A[NE]; const float* B[NE]; };

__device__ __forceinline__ short f2bf(float f) {
  union { float f; unsigned u; } v; v.f = f;
  return (short)((v.u + 0x7FFFu + ((v.u >> 16) & 1u)) >> 16);  // RNE
}

__device__ __forceinline__ float wsum(float v) {
  #pragma unroll
  for (int off = 32; off > 0; off >>= 1) v += __shfl_xor(v, off);
  return v;
}

__device__ __forceinline__ float dot4acc(float4 a, float4 b, float acc) {
  acc = fmaf(a.x, b.x, acc);
  acc = fmaf(a.y, b.y, acc);
  acc = fmaf(a.z, b.z, acc);
  acc = fmaf(a.w, b.w, acc);
  return acc;
}

// ---------------- K0: weights -> AIMG (packed fragment image) + B16; proto prep ------
// AIMG[c][row][q]: bf16x8 of A_global[row][c*32+q*8..], row pitch 32 shorts (64 B),
// chunk stride 12800 shorts. A-operand frag load = 1 KB coalesced per (tile, chunk).
__global__ __launch_bounds__(256) void k_conv(ExpPtrs p, short* __restrict__ AIMG,
                                              short* __restrict__ B16,
                                              const float* __restrict__ proto,
                                              float* __restrict__ wsf,
                                              int* __restrict__ counts) {
  const int e = blockIdx.y;
  const int tid = threadIdx.x;
  const int d = DV[e], dp = DPV[e], dap = DAPV[e], bo = BOV[e], rs = RSV[e];

  if (blockIdx.x == 0) {
    __shared__ float pred[4];
    if (e == 0 && tid < 8) counts[tid] = 0;
    const int w = tid >> 6, lane = tid & 63;
    float v4[4], ss = 0.f;
    #pragma unroll
    for (int i = 0; i < 4; ++i) {
      v4[i] = proto[e * DIM + tid + 256 * i];
      ss = fmaf(v4[i], v4[i], ss);
    }
    ss = wsum(ss);
    if (lane == 0) pred[w] = ss;
    __syncthreads();
    float tot = ((pred[0] + pred[1]) + pred[2]) + pred[3];
    float inv = 1.f / fmaxf(sqrtf(tot), 1e-12f);
    #pragma unroll
    for (int i = 0; i < 4; ++i)
      wsf[PN_OFF + e * DIM + tid + 256 * i] = v4[i] * inv;
  }

  const float* A = p.A[e];
  const float* B = p.B[e];
  const int t0 = blockIdx.x * 256 + tid;

  const int tot = dap * 128;  // rows x (32 chunks x 4 q)
  for (int i = t0; i < tot; i += 16 * 256) {
    int lr = i >> 7, rem = i & 127;
    int c = rem >> 2, q = rem & 3;
    short8v v = (short8v){0, 0, 0, 0, 0, 0, 0, 0};
    if (lr < d) {
      const float* src = A + (size_t)lr * DIM + c * 32 + q * 8;
      #pragma unroll
      for (int j = 0; j < 8; ++j) v[j] = f2bf(src[j]);
    }
    *(short8v*)&AIMG[c * 12800 + (rs + lr) * 32 + q * 8] = v;
  }

  short* Bd = B16 + bo;
  for (int i = t0; i < DIM * dp; i += 16 * 256) {
    int j = i / dp, r = i - j * dp;
    Bd[i] = (r < d) ? f2bf(B[(size_t)j * d + r]) : (short)0;
  }
}

// ---------------- K1: fused sim (f32) + T_all = x * A_all^T ----------
// 2048 blocks x 256 thr; block = 16 tokens, 4 waves. Wave w handles ALL 16 tokens x
// tile quarter {TQ0[w]..+TQN[w]} of the 25 A-tiles; sim experts SE0[w]..+SEN[w]
// (wave 3 also |x|^2). Swapped MFMA operands: lane holds 4 consecutive T-cols of
// one token -> uint2 8-B stores. A-frags direct from L2-resident AIMG. No LDS in
// the main loop; low VGPR (acc[7]) for 5 waves/SIMD occupancy.
__global__ __launch_bounds__(256, 5) void k_simT(const float* __restrict__ x,
                                                 const short* __restrict__ AIMG,
                                                 const float* __restrict__ wsf,
                                                 float* __restrict__ e0,
                                                 float* __restrict__ pr1,
                                                 short* __restrict__ Tall) {
  __shared__ float simS[16][8];
  const int tid = threadIdx.x;
  const int n0 = blockIdx.x * 16;
  const int w = tid >> 6, lane = tid & 63, lo = lane & 15, hi = lane >> 4;

  // zero Tall pad cols (16-31, 48-63, 144-159) for this block's 16 rows
  for (int i = tid; i < 16 * 48; i += 256) {
    int r = i / 48, c2 = i - r * 48;
    int col = (c2 < 16) ? (16 + c2) : ((c2 < 32) ? (32 + c2) : (112 + c2));
    Tall[(size_t)(n0 + r) * TROW + col] = 0;
  }

  const int t0 = TQ0[w], nt = TQN[w];
  const int es = SE0[w], ns = SEN[w];
  const float* xp = x + (size_t)(n0 + lo) * DIM + hi * 8;
  const float* PN = wsf + PN_OFF;

  f32x4 acc[7];
  #pragma unroll
  for (int t = 0; t < 7; ++t) acc[t] = (f32x4){0.f, 0.f, 0.f, 0.f};
  float dk[2] = {0.f, 0.f};
  float xx = 0.f;

  for (int c = 0; c < 32; ++c) {
    float4 x0 = *(const float4*)(xp + c * 32);
    float4 x1 = *(const float4*)(xp + c * 32 + 4);
    short8v af;
    af[0] = f2bf(x0.x); af[1] = f2bf(x0.y); af[2] = f2bf(x0.z); af[3] = f2bf(x0.w);
    af[4] = f2bf(x1.x); af[5] = f2bf(x1.y); af[6] = f2bf(x1.z); af[7] = f2bf(x1.w);

    #pragma unroll
    for (int k = 0; k < 2; ++k) {
      if (k < ns) {
        const float* pp = PN + (es + k) * DIM + c * 32 + hi * 8;
        float4 p0 = *(const float4*)pp;
        float4 p1 = *(const float4*)(pp + 4);
        dk[k] = dot4acc(x0, p0, dot4acc(x1, p1, dk[k]));
      }
    }
    if (w == 3) xx = dot4acc(x0, x0, dot4acc(x1, x1, xx));

    const short* Ac = AIMG + c * 12800 + lo * 32 + hi * 8;
    #pragma unroll
    for (int tt = 0; tt < 7; ++tt) {
      if (tt < nt) {
        short8v Af = *(const short8v*)(Ac + (t0 + tt) * 512);
        acc[tt] = __builtin_amdgcn_mfma_f32_16x16x32_bf16(Af, af, acc[tt], 0, 0, 0);
      }
    }
  }

  // T write: lane (lo,hi) reg j -> token (n0+lo), col TCOL[t]+hi*4+j (8-B packed)
  #pragma unroll
  for (int tt = 0; tt < 7; ++tt) {
    if (tt < nt) {
      const int colb = TCOL[t0 + tt] + hi * 4;
      unsigned u0 = (unsigned short)f2bf(acc[tt][0]) |
                    ((unsigned)(unsigned short)f2bf(acc[tt][1]) << 16);
      unsigned u1 = (unsigned short)f2bf(acc[tt][2]) |
                    ((unsigned)(unsigned short)f2bf(acc[tt][3]) << 16);
      uint2 uv; uv.x = u0; uv.y = u1;
      *(uint2*)&Tall[(size_t)(n0 + lo) * TROW + colb] = uv;
    }
  }

  // sim reduce across hi-slices
  #pragma unroll
  for (int k = 0; k < 2; ++k) {
    dk[k] += __shfl_xor(dk[k], 16);
    dk[k] += __shfl_xor(dk[k], 32);
  }
  if (w == 3) { xx += __shfl_xor(xx, 16); xx += __shfl_xor(xx, 32); }
  if (hi == 0) {
    #pragma unroll
    for (int k = 0; k < 2; ++k)
      if (k < ns) simS[lo][es + k] = dk[k];
    if (w == 3) simS[lo][7] = xx;
  }
  __syncthreads();
  if (tid < 16) {
    int n = n0 + tid;
    float nrm = fmaxf(sqrtf(simS[tid][7]), 1e-12f);
    float ev[8];
    #pragma unroll
    for (int k = 0; k < 7; ++k) ev[k] = expf((simS[tid][k] / nrm) / 0.1f);
    ev[7] = 0.f;
    *(float4*)&e0[(size_t)n * 8]     = make_float4(ev[0], ev[1], ev[2], ev[3]);
    *(float4*)&e0[(size_t)n * 8 + 4] = make_float4(ev[4], ev[5], ev[6], ev[7]);
    #pragma unroll
    for (int k = 0; k < 8; ++k) simS[tid][k] = ev[k];
  }
  __syncthreads();
  if (tid < 8) {
    float s = 0.f;
    for (int r = 0; r < 16; ++r) s += simS[r][tid];
    pr1[blockIdx.x * 8 + tid] = s;
  }
}

#define SUM7(l) (((((((l)[0] + (l)[1]) + (l)[2]) + (l)[3]) + (l)[4]) + (l)[5]) + (l)[6])

// ---------------- sinkhorn passes; each self-reduces prior partials ----------------
template<int DEPTH>
__global__ __launch_bounds__(256) void k_pass(const float* __restrict__ e0,
                                              float* __restrict__ wsf,
                                              const float* __restrict__ src, int nb,
                                              float* __restrict__ prOut,
                                              int* __restrict__ counts,
                                              int* __restrict__ list,
                                              float* __restrict__ lgv) {
  __shared__ float red2[8][33];
  __shared__ float Rcur[8];
  const int tid = threadIdx.x;
  {
    const int k = tid & 7, m = tid >> 3;
    float a = 0.f;
    for (int b = m; b < nb; b += 32) a += src[b * 8 + k];
    red2[k][m] = a;
    __syncthreads();
    if (tid < 8) {
      float s = 0.f;
      for (int mm = 0; mm < 32; ++mm) s += red2[tid][mm];
      Rcur[tid] = s;
      if (blockIdx.x == 0) {
        int roff = (DEPTH == 1) ? R1_OFF : (DEPTH == 2) ? R2_OFF : R3_OFF;
        wsf[roff + tid] = s;
      }
    }
    __syncthreads();
  }

  const int n = blockIdx.x * 256 + tid;
  float4 v0 = *(const float4*)(e0 + (size_t)n * 8);
  float4 v1 = *(const float4*)(e0 + (size_t)n * 8 + 4);
  float l[NE] = {v0.x, v0.y, v0.z, v0.w, v1.x, v1.y, v1.z};
  {
    const float* R1 = (DEPTH == 1) ? Rcur : (wsf + R1_OFF);
    #pragma unroll
    for (int k = 0; k < NE; ++k) l[k] = l[k] / (R1[k] + SEPS);
    float C = SUM7(l);
    #pragma unroll
    for (int k = 0; k < NE; ++k) l[k] = l[k] / (C + SEPS);
  }
  if constexpr (DEPTH >= 2) {
    const float* R2 = (DEPTH == 2) ? Rcur : (wsf + R2_OFF);
    #pragma unroll
    for (int k = 0; k < NE; ++k) l[k] = l[k] / (R2[k] + SEPS);
    float C = SUM7(l);
    #pragma unroll
    for (int k = 0; k < NE; ++k) l[k] = l[k] / (C + SEPS);
  }
  if constexpr (DEPTH >= 3) {
    const float* R3 = Rcur;
    #pragma unroll
    for (int k = 0; k < NE; ++k) l[k] = l[k] / (R3[k] + SEPS);
    float C = SUM7(l);
    #pragma unroll
    for (int k = 0; k < NE; ++k) l[k] = l[k] / (C + SEPS);
  }
  if constexpr (DEPTH == 3) {
    float best = l[0]; int be = 0;
    #pragma unroll
    for (int k = 1; k < NE; ++k) {
      if (l[k] > best) { best = l[k]; be = k; }
    }
    __shared__ int lcnt[8];
    __shared__ int wbase[4][8];
    __shared__ int gbase[8];
    const int w = tid >> 6, lane = tid & 63;
    if (tid < 8) lcnt[tid] = 0;
    __syncthreads();
    int rank = 0;
    #pragma unroll
    for (int k = 0; k < NE; ++k) {
      unsigned long long m = __ballot(be == k);
      if (lane == 0) wbase[w][k] = m ? atomicAdd(&lcnt[k], (int)__popcll(m)) : 0;
      if (be == k) rank = (int)__popcll(m & ((1ull << lane) - 1ull));
    }
    __syncthreads();
    if (tid < 8) gbase[tid] = lcnt[tid] ? atomicAdd(&counts[tid], lcnt[tid]) : 0;
    __syncthreads();
    int pos = gbase[be] + wbase[w][be] + rank;
    list[be * NTOK + pos] = n;
    lgv[n] = logf(best);
  } else {
    __shared__ float red[NE][256];
    #pragma unroll
    for (int k = 0; k < NE; ++k) red[k][tid] = l[k];
    __syncthreads();
    for (int off = 128; off > 0; off >>= 1) {
      if (tid < off) {
        #pragma unroll
        for (int k = 0; k < NE; ++k) red[k][tid] += red[k][tid + off];
      }
      __syncthreads();
    }
    if (tid < NE) prOut[blockIdx.x * 8 + tid] = red[tid][0];
  }
}

// ---------------- phase B: Y = T_all[tok, APRE_e..] * B^T + log(g) ----------------
__device__ __forceinline__ bool walk(int bid, const int* counts,
                                     int& e, int& tile, int& cnt) {
  int rem = bid; e = 0;
  while (true) {
    cnt = counts[e];
    int tiles = (cnt + 15) >> 4;
    if (rem < tiles) { tile = rem; return true; }
    rem -= tiles;
    if (++e == NE) return false;
  }
}

template<int E>
__device__ void phB_impl(const short* __restrict__ Bp,
                         const short* __restrict__ Tall,
                         const int* __restrict__ list_e,
                         const float* __restrict__ lg,
                         int cnt, int tile, float* __restrict__ out) {
  constexpr int DP = DPV[E];
  constexpr int KS2 = DP / 32;
  const int tid = threadIdx.x;
  const int w = tid >> 6, lane = tid & 63;
  const int lo = lane & 15, hi = lane >> 4;
  const int m0 = tile * 16;

  const int myTok = list_e[min(m0 + lo, cnt - 1)];
  short8v tf[KS2];
  #pragma unroll
  for (int ks = 0; ks < KS2; ++ks)
    tf[ks] = *(const short8v*)(Tall + (size_t)myTok * TROW + APRE[E] + ks * 32 + hi * 8);

  int tok[4]; float lgvr[4];
  #pragma unroll
  for (int j = 0; j < 4; ++j) {
    tok[j] = list_e[min(m0 + hi * 4 + j, cnt - 1)];
    lgvr[j] = lg[tok[j]];
  }

  const short* BpL = Bp + (size_t)(w * 256 + lo) * DP + hi * 8;
  #pragma unroll 1
  for (int nt = 0; nt < 16; ++nt) {
    f32x4 acc = (f32x4){0.f, 0.f, 0.f, 0.f};
    #pragma unroll
    for (int ks = 0; ks < KS2; ++ks) {
      short8v bf = *(const short8v*)(BpL + (size_t)nt * 16 * DP + ks * 32);
      acc = __builtin_amdgcn_mfma_f32_16x16x32_bf16(tf[ks], bf, acc, 0, 0, 0);
    }
    #pragma unroll
    for (int j = 0; j < 4; ++j)
      out[(size_t)tok[j] * DIM + w * 256 + nt * 16 + lo] = acc[j] + lgvr[j];
  }
}

__global__ __launch_bounds__(256, 8) void k_phB(const short* __restrict__ B16,
                                                const short* __restrict__ Tall,
                                                const int* __restrict__ list,
                                                const float* __restrict__ lg,
                                                const int* __restrict__ counts,
                                                float* __restrict__ out) {
  int bid = ((int)blockIdx.x * 1024) % NBLK;  // coprime stride: spread heavy experts
  int e, tile, cnt;
  if (!walk(bid, counts, e, tile, cnt)) return;
  switch (e) {
    case 0: phB_impl<0>(B16 + BOV[0], Tall, list + 0 * NTOK, lg, cnt, tile, out); break;
    case 1: phB_impl<1>(B16 + BOV[1], Tall, list + 1 * NTOK, lg, cnt, tile, out); break;
    case 2: phB_impl<2>(B16 + BOV[2], Tall, list + 2 * NTOK, lg, cnt, tile, out); break;
    case 3: phB_impl<3>(B16 + BOV[3], Tall, list + 3 * NTOK, lg, cnt, tile, out); break;
    case 4: phB_impl<4>(B16 + BOV[4], Tall, list + 4 * NTOK, lg, cnt, tile, out); break;
    case 5: phB_impl<5>(B16 + BOV[5], Tall, list + 5 * NTOK, lg, cnt, tile, out); break;
    default: phB_impl<6>(B16 + BOV[6], Tall, list + 6 * NTOK, lg, cnt, tile, out); break;
  }
}

extern "C" void kernel_launch(void* const* d_in, const int* in_sizes, int n_in,
                              void* d_out, int out_size, void* d_ws, size_t ws_size,
                              hipStream_t stream) {
  const float* x     = (const float*)d_in[0];
  const float* proto = (const float*)d_in[1];
  ExpPtrs p;
  for (int e = 0; e < NE; ++e) {
    p.A[e] = (const float*)d_in[2 + 2 * e];
    p.B[e] = (const float*)d_in[3 + 2 * e];
  }
  float* wsf  = (float*)d_ws;
  int*   wsi  = (int*)d_ws;
  short* B16  = (short*)(wsf + B16_OFF);
  short* AIMG = (short*)((char*)d_ws + AIMG_OFF_BYTES);
  short* Tall = (short*)((char*)d_ws + TALL_OFF_BYTES);
  float* out  = (float*)d_out;

  k_conv<<<dim3(16, NE), 256, 0, stream>>>(p, AIMG, B16, proto, wsf, wsi + CNT_OFF);
  k_simT<<<2048, 256, 0, stream>>>(x, AIMG, wsf, wsf + E0_OFF, wsf + PR1_OFF, Tall);
  k_pass<1><<<128, 256, 0, stream>>>(wsf + E0_OFF, wsf, wsf + PR1_OFF, 2048,
                                     wsf + PR2_OFF, nullptr, nullptr, nullptr);
  k_pass<2><<<128, 256, 0, stream>>>(wsf + E0_OFF, wsf, wsf + PR2_OFF, 128,
                                     wsf + PR3_OFF, nullptr, nullptr, nullptr);
  k_pass<3><<<128, 256, 0, stream>>>(wsf + E0_OFF, wsf, wsf + PR3_OFF, 128,
                                     nullptr, wsi + CNT_OFF, wsi + LIST_OFF, wsf + LG_OFF);
  k_phB<<<NBLK, 256, 0, stream>>>(B16, Tall, wsi + LIST_OFF, wsf + LG_OFF,
                                  wsi + CNT_OFF, out);
}

// Round 11
// 204.250 us; speedup vs baseline: 1.6198x; 1.6198x over previous
//
#include <hip/hip_runtime.h>
#include <math.h>

#define NTOK 32768
#define DIM  1024
#define NE   7

// ws layout (4-byte units), ~3.94 MB
#define PN_OFF   0        // 7*1024 normalized prototypes (f32)
#define R1_OFF   7168
#define R2_OFF   7176
#define R3_OFF   7184
#define CNT_OFF  7192     // 8 ints
#define PR1_OFF  7200     // 2048*8
#define PR2_OFF  23584    // 128*8
#define PR3_OFF  24608    // 128*8
#define E0_OFF   25632    // NTOK*8 exp(sim/kappa)
#define LG_OFF   287776   // NTOK: log(top-1 gate)
#define LIST_OFF 320544   // NE*NTOK ints
#define A16_OFF  549920   // bf16 A weights (padded rows)
#define B16_OFF  754720   // bf16 B weights (padded cols)
#define NBLK 2055

#define SEPS 1e-6f

typedef __attribute__((ext_vector_type(8))) short short8v;
typedef __attribute__((ext_vector_type(4))) float f32x4;

// per-expert geometry
constexpr int DV[7]   = {8, 16, 32, 48, 64, 96, 128};
constexpr int DPV[7]  = {32, 32, 32, 64, 64, 96, 128};   // K-padded (mult 32)
constexpr int DAPV[7] = {16, 16, 32, 48, 64, 96, 128};   // N-padded (mult 16)
constexpr int AOV[7]  = {0, 16384, 32768, 65536, 114688, 180224, 278528};
constexpr int BOV[7]  = {0, 32768, 65536, 98304, 163840, 229376, 327680};

struct ExpPtrs { const float* A[NE]; const float* B[NE]; };

__device__ __forceinline__ short f2bf(float f) {
  union { float f; unsigned u; } v; v.f = f;
  return (short)((v.u + 0x7FFFu + ((v.u >> 16) & 1u)) >> 16);  // RNE
}

__device__ __forceinline__ float wsum(float v) {
  #pragma unroll
  for (int off = 32; off > 0; off >>= 1) v += __shfl_xor(v, off);
  return v;
}

__device__ __forceinline__ float dot4acc(float4 a, float4 b, float acc) {
  acc = fmaf(a.x, b.x, acc);
  acc = fmaf(a.y, b.y, acc);
  acc = fmaf(a.z, b.z, acc);
  acc = fmaf(a.w, b.w, acc);
  return acc;
}

__device__ __forceinline__ void ecfg(int e, int& d, int& dp, int& dap, int& ao, int& bo) {
  switch (e) {
    case 0: d = 8;   dp = 32;  dap = 16;  ao = 0;      bo = 0;      break;
    case 1: d = 16;  dp = 32;  dap = 16;  ao = 16384;  bo = 32768;  break;
    case 2: d = 32;  dp = 32;  dap = 32;  ao = 32768;  bo = 65536;  break;
    case 3: d = 48;  dp = 64;  dap = 48;  ao = 65536;  bo = 98304;  break;
    case 4: d = 64;  dp = 64;  dap = 64;  ao = 114688; bo = 163840; break;
    case 5: d = 96;  dp = 96;  dap = 96;  ao = 180224; bo = 229376; break;
    default: d = 128; dp = 128; dap = 128; ao = 278528; bo = 327680; break;
  }
}

// ---------------- K0: bf16 weight conversion + (block x==0) proto prep ----------------
__global__ __launch_bounds__(256) void k_conv(ExpPtrs p, short* __restrict__ A16,
                                              short* __restrict__ B16,
                                              const float* __restrict__ proto,
                                              float* __restrict__ wsf,
                                              int* __restrict__ counts) {
  const int e = blockIdx.y;
  const int tid = threadIdx.x;
  int d, dp, dap, ao, bo;
  ecfg(e, d, dp, dap, ao, bo);

  if (blockIdx.x == 0) {
    __shared__ float pred[4];
    if (e == 0 && tid < 8) counts[tid] = 0;
    const int w = tid >> 6, lane = tid & 63;
    float v4[4], ss = 0.f;
    #pragma unroll
    for (int i = 0; i < 4; ++i) {
      v4[i] = proto[e * DIM + tid + 256 * i];
      ss = fmaf(v4[i], v4[i], ss);
    }
    ss = wsum(ss);
    if (lane == 0) pred[w] = ss;
    __syncthreads();
    float tot = ((pred[0] + pred[1]) + pred[2]) + pred[3];
    float inv = 1.f / fmaxf(sqrtf(tot), 1e-12f);
    #pragma unroll
    for (int i = 0; i < 4; ++i)
      wsf[PN_OFF + e * DIM + tid + 256 * i] = v4[i] * inv;
  }

  const float* A = p.A[e];
  const float* B = p.B[e];
  short* Ad = A16 + ao;
  short* Bd = B16 + bo;
  const int t0 = blockIdx.x * 256 + tid;
  for (int i = t0; i < dap * DIM; i += 16 * 256) {
    int row = i >> 10;
    Ad[i] = (row < d) ? f2bf(A[i]) : (short)0;
  }
  for (int i = t0; i < DIM * dp; i += 16 * 256) {
    int j = i / dp, r = i - j * dp;
    Bd[i] = (r < d) ? f2bf(B[j * d + r]) : (short)0;
  }
}

// ---------------- K1: sim -> e0 = exp(sim/kappa), block partials of R1 ----------------
__global__ __launch_bounds__(256) void k_sim(const float* __restrict__ x,
                                             const float* __restrict__ wsf,
                                             float* __restrict__ e0,
                                             float* __restrict__ pr1) {
  const int tid = threadIdx.x, w = tid >> 6, lane = tid & 63;
  const float4* pn4 = (const float4*)(wsf + PN_OFF);
  const int gw = blockIdx.x * 4 + w;
  float r1a[NE] = {0.f, 0.f, 0.f, 0.f, 0.f, 0.f, 0.f};
  for (int it = 0; it < 4; ++it) {
    const int n = gw + 8192 * it;
    const float4* xr4 = (const float4*)(x + (size_t)n * DIM);
    float xx = 0.f;
    float dk[NE] = {0.f, 0.f, 0.f, 0.f, 0.f, 0.f, 0.f};
    #pragma unroll
    for (int i = 0; i < 4; ++i) {
      float4 xv = xr4[lane + 64 * i];
      xx = dot4acc(xv, xv, xx);
      #pragma unroll
      for (int k = 0; k < NE; ++k)
        dk[k] = dot4acc(xv, pn4[k * 256 + lane + 64 * i], dk[k]);
    }
    xx = wsum(xx);
    #pragma unroll
    for (int k = 0; k < NE; ++k) dk[k] = wsum(dk[k]);
    if (lane == 0) {
      float nrm = fmaxf(sqrtf(xx), 1e-12f);
      #pragma unroll
      for (int k = 0; k < NE; ++k) {
        float ev = expf((dk[k] / nrm) / 0.1f);
        e0[(size_t)n * 8 + k] = ev;
        r1a[k] += ev;
      }
    }
  }
  __shared__ float red[4][8];
  if (lane == 0) {
    #pragma unroll
    for (int k = 0; k < NE; ++k) red[w][k] = r1a[k];
  }
  __syncthreads();
  if (tid == 0) {
    #pragma unroll
    for (int k = 0; k < NE; ++k)
      pr1[blockIdx.x * 8 + k] = ((red[0][k] + red[1][k]) + red[2][k]) + red[3][k];
  }
}

#define SUM7(l) (((((((l)[0] + (l)[1]) + (l)[2]) + (l)[3]) + (l)[4]) + (l)[5]) + (l)[6])

// ---------------- sinkhorn passes; each self-reduces prior partials ----------------
template<int DEPTH>
__global__ __launch_bounds__(256) void k_pass(const float* __restrict__ e0,
                                              float* __restrict__ wsf,
                                              const float* __restrict__ src, int nb,
                                              float* __restrict__ prOut,
                                              int* __restrict__ counts,
                                              int* __restrict__ list,
                                              float* __restrict__ lgv) {
  __shared__ float red2[8][33];
  __shared__ float Rcur[8];
  const int tid = threadIdx.x;
  {
    const int k = tid & 7, m = tid >> 3;
    float a = 0.f;
    for (int b = m; b < nb; b += 32) a += src[b * 8 + k];
    red2[k][m] = a;
    __syncthreads();
    if (tid < 8) {
      float s = 0.f;
      for (int mm = 0; mm < 32; ++mm) s += red2[tid][mm];
      Rcur[tid] = s;
      if (blockIdx.x == 0) {
        int roff = (DEPTH == 1) ? R1_OFF : (DEPTH == 2) ? R2_OFF : R3_OFF;
        wsf[roff + tid] = s;
      }
    }
    __syncthreads();
  }

  const int n = blockIdx.x * 256 + tid;
  float4 v0 = *(const float4*)(e0 + (size_t)n * 8);
  float4 v1 = *(const float4*)(e0 + (size_t)n * 8 + 4);
  float l[NE] = {v0.x, v0.y, v0.z, v0.w, v1.x, v1.y, v1.z};
  {
    const float* R1 = (DEPTH == 1) ? Rcur : (wsf + R1_OFF);
    #pragma unroll
    for (int k = 0; k < NE; ++k) l[k] = l[k] / (R1[k] + SEPS);
    float C = SUM7(l);
    #pragma unroll
    for (int k = 0; k < NE; ++k) l[k] = l[k] / (C + SEPS);
  }
  if constexpr (DEPTH >= 2) {
    const float* R2 = (DEPTH == 2) ? Rcur : (wsf + R2_OFF);
    #pragma unroll
    for (int k = 0; k < NE; ++k) l[k] = l[k] / (R2[k] + SEPS);
    float C = SUM7(l);
    #pragma unroll
    for (int k = 0; k < NE; ++k) l[k] = l[k] / (C + SEPS);
  }
  if constexpr (DEPTH >= 3) {
    const float* R3 = Rcur;
    #pragma unroll
    for (int k = 0; k < NE; ++k) l[k] = l[k] / (R3[k] + SEPS);
    float C = SUM7(l);
    #pragma unroll
    for (int k = 0; k < NE; ++k) l[k] = l[k] / (C + SEPS);
  }
  if constexpr (DEPTH == 3) {
    float best = l[0]; int be = 0;
    #pragma unroll
    for (int k = 1; k < NE; ++k) {
      if (l[k] > best) { best = l[k]; be = k; }
    }
    // two-level slot reservation: wave ballot -> LDS counts -> 7 global atomics/block
    __shared__ int lcnt[8];
    __shared__ int wbase[4][8];
    __shared__ int gbase[8];
    const int w = tid >> 6, lane = tid & 63;
    if (tid < 8) lcnt[tid] = 0;
    __syncthreads();
    int rank = 0;
    #pragma unroll
    for (int k = 0; k < NE; ++k) {
      unsigned long long m = __ballot(be == k);
      if (lane == 0) wbase[w][k] = m ? atomicAdd(&lcnt[k], (int)__popcll(m)) : 0;
      if (be == k) rank = (int)__popcll(m & ((1ull << lane) - 1ull));
    }
    __syncthreads();
    if (tid < 8) gbase[tid] = lcnt[tid] ? atomicAdd(&counts[tid], lcnt[tid]) : 0;
    __syncthreads();
    int pos = gbase[be] + wbase[w][be] + rank;
    list[be * NTOK + pos] = n;
    lgv[n] = logf(best);
  } else {
    __shared__ float red[NE][256];
    #pragma unroll
    for (int k = 0; k < NE; ++k) red[k][tid] = l[k];
    __syncthreads();
    for (int off = 128; off > 0; off >>= 1) {
      if (tid < off) {
        #pragma unroll
        for (int k = 0; k < NE; ++k) red[k][tid] += red[k][tid + off];
      }
      __syncthreads();
    }
    if (tid < NE) prOut[blockIdx.x * 8 + tid] = red[tid][0];
  }
}

// ---------------- routed expert LoRA via bf16 MFMA, K-split + col-split ----------------
// Block = 16 tokens, 4 waves. Flattened 1-D grid with COPRIME PERMUTE so heavy
// e6 tiles interleave through the dispatch (no low-occupancy tail).
// Phase 1: wave w: partial T over K-chunk [w*256, +256), depth-2 x prefetch;
//          f32 partials in LDS (2 regions), reg combine, bf16 T overlays P.
// Phase 2: wave w: output cols [w*256, +256); out = y + log(g).
template<int E>
__device__ void expert_mfma(const float* __restrict__ x,
                            const short* __restrict__ A16,
                            const short* __restrict__ B16,
                            const int* __restrict__ list_e,
                            const float* __restrict__ lg,
                            int cnt, int tile, float* __restrict__ out,
                            char* lds) {
  constexpr int DP = DPV[E], DAP = DAPV[E];
  constexpr int NT1 = DAP / 16;
  constexpr int KS2 = DP / 32;
  constexpr int PP  = DAP + 4;
  constexpr int SP  = DP + 8;
  float* P = (float*)lds;         // [2][16][PP]
  short* T = (short*)lds;         // [16][SP] — overlays P after reg-staged combine

  const short* Am = A16 + AOV[E];
  const short* Bp = B16 + BOV[E];
  const int tid = threadIdx.x;
  const int w = tid >> 6, lane = tid & 63;
  const int lo = lane & 15, hi = lane >> 4;
  const int m0 = tile * 16;

  // ---- phase 1: partial over K-chunk of 256, depth-2 prefetch ----
  const int myTok = list_e[min(m0 + lo, cnt - 1)];
  const float* xp = x + (size_t)myTok * DIM + w * 256 + hi * 8;
  const short* ApL = Am + lo * DIM + w * 256 + hi * 8;

  f32x4 acc1[NT1];
  #pragma unroll
  for (int t = 0; t < NT1; ++t) acc1[t] = (f32x4){0.f, 0.f, 0.f, 0.f};

  float4 nx0 = *(const float4*)(xp);
  float4 nx1 = *(const float4*)(xp + 4);
  float4 mx0 = *(const float4*)(xp + 32);
  float4 mx1 = *(const float4*)(xp + 36);
  #pragma unroll
  for (int kc = 0; kc < 256; kc += 32) {
    float4 x0 = nx0, x1 = nx1;
    nx0 = mx0; nx1 = mx1;
    if (kc + 64 < 256) {
      mx0 = *(const float4*)(xp + kc + 64);
      mx1 = *(const float4*)(xp + kc + 68);
    }
    short8v af;
    af[0] = f2bf(x0.x); af[1] = f2bf(x0.y); af[2] = f2bf(x0.z); af[3] = f2bf(x0.w);
    af[4] = f2bf(x1.x); af[5] = f2bf(x1.y); af[6] = f2bf(x1.z); af[7] = f2bf(x1.w);
    #pragma unroll
    for (int t = 0; t < NT1; ++t) {
      short8v bf = *(const short8v*)(ApL + t * 16 * DIM + kc);
      acc1[t] = __builtin_amdgcn_mfma_f32_16x16x32_bf16(af, bf, acc1[t], 0, 0, 0);
    }
  }

  // ---- LDS reduce: waves 0,1 write; waves 2,3 add ----
  float* Pw = P + (w & 1) * 16 * PP;
  if (w < 2) {
    #pragma unroll
    for (int t = 0; t < NT1; ++t)
      #pragma unroll
      for (int j = 0; j < 4; ++j)
        Pw[(hi * 4 + j) * PP + t * 16 + lo] = acc1[t][j];
  }
  __syncthreads();
  if (w >= 2) {
    #pragma unroll
    for (int t = 0; t < NT1; ++t)
      #pragma unroll
      for (int j = 0; j < 4; ++j)
        Pw[(hi * 4 + j) * PP + t * 16 + lo] += acc1[t][j];
  }
  __syncthreads();
  // combine -> regs -> barrier -> bf16 T (overlaying P)
  constexpr int NITEM = (16 * DP + 255) / 256;
  float vloc[NITEM];
  #pragma unroll
  for (int it = 0; it < NITEM; ++it) {
    int i = tid + it * 256;
    float v = 0.f;
    if (i < 16 * DP) {
      int r = i / DP, c = i - r * DP;
      if (c < DAP) v = P[r * PP + c] + P[(16 + r) * PP + c];
    }
    vloc[it] = v;
  }
  __syncthreads();
  #pragma unroll
  for (int it = 0; it < NITEM; ++it) {
    int i = tid + it * 256;
    if (i < 16 * DP) {
      int r = i / DP, c = i - r * DP;
      T[r * SP + c] = f2bf(vloc[it]);
    }
  }
  __syncthreads();

  // ---- phase 2: cols [w*256, +256) ----
  short8v tf[KS2];
  #pragma unroll
  for (int ks = 0; ks < KS2; ++ks)
    tf[ks] = *(const short8v*)(T + lo * SP + ks * 32 + hi * 8);

  float  lgvr[4];
  float* op[4];
  #pragma unroll
  for (int j = 0; j < 4; ++j) {
    int t = list_e[min(m0 + hi * 4 + j, cnt - 1)];
    lgvr[j] = lg[t];
    op[j] = out + (size_t)t * DIM + w * 256 + lo;
  }

  const short* BpL = Bp + (size_t)(w * 256 + lo) * DP + hi * 8;
  #pragma unroll 4
  for (int nt = 0; nt < 16; ++nt) {
    f32x4 acc = (f32x4){0.f, 0.f, 0.f, 0.f};
    #pragma unroll
    for (int ks = 0; ks < KS2; ++ks) {
      short8v bf = *(const short8v*)(BpL + (size_t)nt * 16 * DP + ks * 32);
      acc = __builtin_amdgcn_mfma_f32_16x16x32_bf16(tf[ks], bf, acc, 0, 0, 0);
    }
    #pragma unroll
    for (int j = 0; j < 4; ++j)
      op[j][nt * 16] = acc[j] + lgvr[j];
  }
}

__global__ __launch_bounds__(256) void k_expert(const float* __restrict__ x,
                                                const short* __restrict__ A16,
                                                const short* __restrict__ B16,
                                                const int* __restrict__ list,
                                                const float* __restrict__ lg,
                                                const int* __restrict__ counts,
                                                float* __restrict__ out) {
  __shared__ __align__(16) char lds[16896];  // 2*16*(128+4)*4
  // coprime permute (gcd(1024,2055)=1 -> bijective): spread heavy e6 tiles
  int bid = ((int)blockIdx.x * 1024) % NBLK;
  // find (expert, tile) via prefix over ceil(counts[e]/16)
  int rem = bid;
  int e = 0, cnt;
  while (true) {
    cnt = counts[e];
    int tiles = (cnt + 15) >> 4;
    if (rem < tiles) break;
    rem -= tiles;
    if (++e == NE) return;
  }
  switch (e) {
    case 0: expert_mfma<0>(x, A16, B16, list + 0 * NTOK, lg, cnt, rem, out, lds); break;
    case 1: expert_mfma<1>(x, A16, B16, list + 1 * NTOK, lg, cnt, rem, out, lds); break;
    case 2: expert_mfma<2>(x, A16, B16, list + 2 * NTOK, lg, cnt, rem, out, lds); break;
    case 3: expert_mfma<3>(x, A16, B16, list + 3 * NTOK, lg, cnt, rem, out, lds); break;
    case 4: expert_mfma<4>(x, A16, B16, list + 4 * NTOK, lg, cnt, rem, out, lds); break;
    case 5: expert_mfma<5>(x, A16, B16, list + 5 * NTOK, lg, cnt, rem, out, lds); break;
    case 6: expert_mfma<6>(x, A16, B16, list + 6 * NTOK, lg, cnt, rem, out, lds); break;
  }
}

extern "C" void kernel_launch(void* const* d_in, const int* in_sizes, int n_in,
                              void* d_out, int out_size, void* d_ws, size_t ws_size,
                              hipStream_t stream) {
  const float* x     = (const float*)d_in[0];
  const float* proto = (const float*)d_in[1];
  ExpPtrs p;
  for (int e = 0; e < NE; ++e) {
    p.A[e] = (const float*)d_in[2 + 2 * e];
    p.B[e] = (const float*)d_in[3 + 2 * e];
  }
  float* wsf = (float*)d_ws;
  int*   wsi = (int*)d_ws;
  short* A16 = (short*)(wsf + A16_OFF);
  short* B16 = (short*)(wsf + B16_OFF);
  float* out = (float*)d_out;

  k_conv<<<dim3(16, NE), 256, 0, stream>>>(p, A16, B16, proto, wsf, wsi + CNT_OFF);
  k_sim<<<2048, 256, 0, stream>>>(x, wsf, wsf + E0_OFF, wsf + PR1_OFF);
  k_pass<1><<<128, 256, 0, stream>>>(wsf + E0_OFF, wsf, wsf + PR1_OFF, 2048,
                                     wsf + PR2_OFF, nullptr, nullptr, nullptr);
  k_pass<2><<<128, 256, 0, stream>>>(wsf + E0_OFF, wsf, wsf + PR2_OFF, 128,
                                     wsf + PR3_OFF, nullptr, nullptr, nullptr);
  k_pass<3><<<128, 256, 0, stream>>>(wsf + E0_OFF, wsf, wsf + PR3_OFF, 128,
                                     nullptr, wsi + CNT_OFF, wsi + LIST_OFF, wsf + LG_OFF);
  k_expert<<<NBLK, 256, 0, stream>>>(x, A16, B16, wsi + LIST_OFF,
                                     wsf + LG_OFF, wsi + CNT_OFF, out);
}